// Round 20
// baseline (64.699 us; speedup 1.0000x reference)
//
#include <hip/hip_runtime.h>

#define BATCH 512
#define TT    1024
#define NST   64
#define NSYM  32
#define NCH   64      // chunks per chain (4 waves x 16 MFMA columns)
#define CLEN  16      // TT / NCH
#define WARM  6       // warmup steps (mixing 0.16^6 ~ 2e-5; ll err ~2e-3 << 14.5)
#define LN2F  0.69314718055994530942f

#define AP_MV    6400   // dword offset: packed matvec A-frags  [4mt][2kc][64][4]
#define AP_EM    8448   // dword offset: packed emission A-frags [4mt][64][4]
#define WS_STATS 9472   // float offset: per-(chain,chunk) Lstart  [512][64]

typedef _Float16 f16x8 __attribute__((ext_vector_type(8)));
typedef float    f32x4 __attribute__((ext_vector_type(4)));

#define MFMA_F16(a,b,c) __builtin_amdgcn_mfma_f32_16x16x32_f16(a,b,c,0,0,0)

__device__ __forceinline__ unsigned pkrtz_u(float a, float b) {
    return __builtin_bit_cast(unsigned, __builtin_amdgcn_cvt_pkrtz(a, b));
}

// slot(g, r) -> k within a K=32 chunk (shared by A-pack and B-pack; the k-sum
// is permutation invariant so any true hw map works if both sides agree).
__device__ __forceinline__ int sigma_k(int g, int r) {
    return (r < 4) ? (4 * g + r) : (16 + 4 * g + (r - 4));
}

__device__ __forceinline__ f16x8 pk8(float a0, float a1, float a2, float a3,
                                     float a4, float a5, float a6, float a7) {
    union U { unsigned u[4]; f16x8 v; } u;
    u.u[0] = pkrtz_u(a0, a1);
    u.u[1] = pkrtz_u(a2, a3);
    u.u[2] = pkrtz_u(a4, a5);
    u.u[3] = pkrtz_u(a6, a7);
    return u.v;
}

// xs16 swizzle (u32-index domain): XOR row bits [8:10] into bits [2:4].
// Bijective; preserves bits 0-1 (b64 groups contiguous); spreads the 16
// same-g lanes across 8 bank-classes -> ~2-way conflicts (free, m136).
__device__ __forceinline__ int swz16(int d) { return d ^ (((d >> 8) & 7) << 2); }

// ---------------------------------------------------------------------------
// Prep: softmaxes + MFMA fragment packing (unchanged).
// ---------------------------------------------------------------------------
__global__ __launch_bounds__(64) void hmm_prep(
    const float* __restrict__ em, const float* __restrict__ tr,
    const float* __restrict__ ini, float* __restrict__ ws)
{
    const int n = threadIdx.x;

    {
        float a[64];
        float m = -1e30f;
        #pragma unroll
        for (int j = 0; j < 64; ++j) { a[j] = tr[n * 64 + j]; m = fmaxf(m, a[j]); }
        float s = 0.f;
        #pragma unroll
        for (int j = 0; j < 64; ++j) { a[j] = __expf(a[j] - m); s += a[j]; }
        const float inv = 1.f / s;
        #pragma unroll
        for (int j = 0; j < 64; ++j) ws[n * 64 + j] = a[j] * inv;
    }
    {
        float bv[32];
        float m = -1e30f;
        #pragma unroll
        for (int j = 0; j < 32; ++j) { bv[j] = em[n * 32 + j]; m = fmaxf(m, bv[j]); }
        float s = 0.f;
        #pragma unroll
        for (int j = 0; j < 32; ++j) { bv[j] = __expf(bv[j] - m); s += bv[j]; }
        const float inv = 1.f / s;
        #pragma unroll
        for (int j = 0; j < 32; ++j) ws[4096 + n * 32 + j] = bv[j] * inv;
    }
    {
        float v = ini[n];
        float m = v;
        #pragma unroll
        for (int off = 32; off; off >>= 1) m = fmaxf(m, __shfl_xor(m, off, 64));
        const float e = __expf(v - m);
        float s = e;
        #pragma unroll
        for (int off = 32; off; off >>= 1) s += __shfl_xor(s, off, 64);
        ws[6144 + n] = e / s;
    }

    __syncthreads();

    const int g   = n >> 4;
    const int cl  = n & 15;
    unsigned* wsu = (unsigned*)ws;

    #pragma unroll
    for (int mt = 0; mt < 4; ++mt) {
        #pragma unroll
        for (int kc = 0; kc < 2; ++kc) {
            #pragma unroll
            for (int p = 0; p < 4; ++p) {
                const int k0 = sigma_k(g, 2 * p);
                const int k1 = sigma_k(g, 2 * p + 1);
                const int m  = 16 * mt + cl;
                const float a0 = ws[(32 * kc + k0) * 64 + m];
                const float a1 = ws[(32 * kc + k1) * 64 + m];
                wsu[AP_MV + ((mt * 2 + kc) * 64 + n) * 4 + p] = pkrtz_u(a0, a1);
            }
        }
        #pragma unroll
        for (int p = 0; p < 4; ++p) {
            const int k0 = sigma_k(g, 2 * p);
            const int k1 = sigma_k(g, 2 * p + 1);
            const int st = 16 * mt + cl;
            const float b0 = ws[4096 + st * 32 + k0];
            const float b1 = ws[4096 + st * 32 + k1];
            wsu[AP_EM + (mt * 64 + n) * 4 + p] = pkrtz_u(b0, b1);
        }
    }
}

// ---------------------------------------------------------------------------
// MFMA scan v4: R19 structure (LDS f16-packed x window, chained matvec MFMA)
// + WARM=6 + rescale every 4th step only.  The power-of-2 rescale exists
// solely to keep h in f32 range (exponent drift ~ -1/step), so applying it
// at (k&3)==1 -- with Esum updated exactly when sc is applied -- keeps
// ll = log(p) + Esum*ln2 exact at every step while deleting the readlane/
// exponent-build and 16 Esc muls from 3/4 of steps.
// ---------------------------------------------------------------------------
__global__ __launch_bounds__(64, 1) void hmm_scan(
    const float* __restrict__ inputs, float* __restrict__ ws,
    float* __restrict__ out)
{
    const int lane = threadIdx.x;
    const int col  = lane & 15;
    const int g    = lane >> 4;
    const int b    = blockIdx.x >> 2;
    const int w    = blockIdx.x & 3;
    const int c    = 16 * w + col;
    const int t0   = c * CLEN;
    const bool isc0 = (c == 0);

    __shared__ unsigned xs16[272 * 16];   // f16-packed window rows [256w-16, 256w+256)

    f16x8 Amv[4][2], Aem[4];
    {
        const int4* mvp = (const int4*)((const unsigned*)ws + AP_MV);
        const int4* emp = (const int4*)((const unsigned*)ws + AP_EM);
        #pragma unroll
        for (int mt = 0; mt < 4; ++mt) {
            Amv[mt][0] = __builtin_bit_cast(f16x8, mvp[(mt * 2 + 0) * 64 + lane]);
            Amv[mt][1] = __builtin_bit_cast(f16x8, mvp[(mt * 2 + 1) * 64 + lane]);
            Aem[mt]    = __builtin_bit_cast(f16x8, emp[mt * 64 + lane]);
        }
    }

    const float* __restrict__ xp = inputs + (size_t)b * (TT * NSYM);
    float* __restrict__ op       = out    + (size_t)b * (TT * 65);

    // ---- stage + pack x window: 272 rows x 16 u32 ----
    #pragma unroll
    for (int i = 0; i < 17; ++i) {
        const int d   = (i * 64 + lane) * 4;   // u32 index, 4-aligned
        const int row = d >> 4;                // 0..271
        const int sy  = (d & 15) * 2;          // source symbol 0,8,16,24
        int grow = 256 * w - 16 + row;
        grow = grow < 0 ? 0 : grow;
        const float* src = xp + (size_t)grow * 32 + sy;
        const float4 a  = *(const float4*)(src);
        const float4 bq = *(const float4*)(src + 4);
        unsigned* pdst = &xs16[swz16(d)];
        pdst[0] = pkrtz_u(a.x, a.y);
        pdst[1] = pkrtz_u(a.z, a.w);
        pdst[2] = pkrtz_u(bq.x, bq.y);
        pdst[3] = pkrtz_u(bq.z, bq.w);
    }
    __syncthreads();

    // x B-operand for step k: pairs {2g,2g+1, 8+2g,8+2g+1} of window row
    // col*16+k+16 -- matches sigma_k slot layout.
    auto ldx = [&](int k) -> f16x8 {
        const int row = col * 16 + k + 16;
        const int d0  = row * 16 + 2 * g;
        const int d1  = d0 + 8;
        union { unsigned u[4]; f16x8 v; } r;
        const uint2 lo = *(const uint2*)&xs16[swz16(d0)];
        const uint2 hi = *(const uint2*)&xs16[swz16(d1)];
        r.u[0] = lo.x; r.u[1] = lo.y; r.u[2] = hi.x; r.u[3] = hi.y;
        return r.v;
    };

    float hD[4][4];
    #pragma unroll
    for (int mt = 0; mt < 4; ++mt)
        #pragma unroll
        for (int r = 0; r < 4; ++r) hD[mt][r] = 1.0f;
    int Esum = 0;

    const f32x4 z4 = {0.f, 0.f, 0.f, 0.f};

    // k must be a compile-time literal at each call site (loops fully
    // unrolled) so the (k&3) rescale predicate folds.
    auto step = [&](int k, bool store_) {
        if (store_) {
            float p = 0.f;
            #pragma unroll
            for (int mt = 0; mt < 4; ++mt)
                #pragma unroll
                for (int r = 0; r < 4; ++r) p += hD[mt][r];
            p += __shfl_xor(p, 16, 64);
            p += __shfl_xor(p, 32, 64);
            const float rS = __builtin_amdgcn_rcpf(p);
            float* rowp = op + (size_t)(t0 + k - 1) * 65;
            #pragma unroll
            for (int mt = 0; mt < 4; ++mt) {
                const float4 v4 = {hD[mt][0] * rS, hD[mt][1] * rS,
                                   hD[mt][2] * rS, hD[mt][3] * rS};
                *(float4*)(rowp + 16 * mt + 4 * g) = v4;
            }
            if (g == 0) rowp[64] = __logf(p) + (float)Esum * LN2F;
        }
        // ---- rescale only every 4th step (exponent drift ~ -1/step) ----
        const bool resc = ((k & 3) == 1);
        float sc = 1.0f;
        if (resc) {
            const int pb = __builtin_amdgcn_readlane(__float_as_int(hD[0][0]), 15);
            int ex = (pb >> 23) & 255;
            ex = ex < 1 ? 1 : (ex > 253 ? 253 : ex);
            sc = __uint_as_float((unsigned)(254 - ex) << 23);   // 2^(127-ex)
            Esum += ex - 127;
        }
        const f16x8 bx = ldx(k);
        f32x4 Esc[4];
        #pragma unroll
        for (int mt = 0; mt < 4; ++mt) {
            const f32x4 E = MFMA_F16(Aem[mt], bx, z4);
            if (resc) {
                Esc[mt][0] = E[0] * sc; Esc[mt][1] = E[1] * sc;
                Esc[mt][2] = E[2] * sc; Esc[mt][3] = E[3] * sc;
            } else {
                Esc[mt] = E;
            }
        }
        const f16x8 bh0 = pk8(hD[0][0], hD[0][1], hD[0][2], hD[0][3],
                              hD[1][0], hD[1][1], hD[1][2], hD[1][3]);
        const f16x8 bh1 = pk8(hD[2][0], hD[2][1], hD[2][2], hD[2][3],
                              hD[3][0], hD[3][1], hD[3][2], hD[3][3]);
        #pragma unroll
        for (int mt = 0; mt < 4; ++mt) {
            const f32x4 mv = MFMA_F16(Amv[mt][1], bh1,
                              MFMA_F16(Amv[mt][0], bh0, z4));
            hD[mt][0] = Esc[mt][0] * mv[0];
            hD[mt][1] = Esc[mt][1] * mv[1];
            hD[mt][2] = Esc[mt][2] * mv[2];
            hD[mt][3] = Esc[mt][3] * mv[3];
        }
    };

    // warmup k = -6..-1 (no outputs; rescale folds per literal k)
    #pragma unroll
    for (int k = -WARM; k < 0; ++k) step(k, false);

    // Lstart (state at t0-1)
    float Lstart;
    {
        float p = 0.f;
        #pragma unroll
        for (int mt = 0; mt < 4; ++mt)
            #pragma unroll
            for (int r = 0; r < 4; ++r) p += hD[mt][r];
        p += __shfl_xor(p, 16, 64);
        p += __shfl_xor(p, 32, 64);
        Lstart = __logf(p) + (float)Esum * LN2F;
    }
    Lstart = isc0 ? 0.f : Lstart;

    // k = 0: silent step (row t0-1 belongs to chunk c-1)
    step(0, false);

    // chunk-0 exact restart: h_0 = E_0 o I   (ldx(0) of col 0 = global row 0)
    {
        const f16x8 bx0 = ldx(0);
        #pragma unroll
        for (int mt = 0; mt < 4; ++mt) {
            const f32x4 E0 = MFMA_F16(Aem[mt], bx0, z4);
            const float4 iv = *(const float4*)(ws + 6144 + 16 * mt + 4 * g);
            const float ivv[4] = {iv.x, iv.y, iv.z, iv.w};
            #pragma unroll
            for (int r = 0; r < 4; ++r)
                if (isc0) hD[mt][r] = E0[r] * ivv[r];
        }
        if (isc0) Esum = 0;
    }

    // main: k = 1..15, outputs for rows t0..t0+14
    #pragma unroll
    for (int k = 1; k <= 15; ++k) step(k, true);

    // epilogue: row t0+15 (local Lend) + Lstart stat
    {
        float p = 0.f;
        #pragma unroll
        for (int mt = 0; mt < 4; ++mt)
            #pragma unroll
            for (int r = 0; r < 4; ++r) p += hD[mt][r];
        p += __shfl_xor(p, 16, 64);
        p += __shfl_xor(p, 32, 64);
        const float rS = __builtin_amdgcn_rcpf(p);
        float* rowp = op + (size_t)(t0 + CLEN - 1) * 65;
        #pragma unroll
        for (int mt = 0; mt < 4; ++mt) {
            const float4 v4 = {hD[mt][0] * rS, hD[mt][1] * rS,
                               hD[mt][2] * rS, hD[mt][3] * rS};
            *(float4*)(rowp + 16 * mt + 4 * g) = v4;
        }
        if (g == 0) {
            rowp[64] = __logf(p) + (float)Esum * LN2F;   // local Lend
            ws[WS_STATS + (size_t)b * NCH + c] = Lstart;
        }
    }
}

// ---------------------------------------------------------------------------
// Fixup: per chain, D_c = Lend_c(local, from out) - Lstart_c; exclusive prefix
// O_c; ll[t] += O_{t/16} - Lstart_{t/16}.  Chunk 0: O=0, Ls=0.
// ---------------------------------------------------------------------------
__global__ __launch_bounds__(64) void hmm_fix(
    const float* __restrict__ ws, float* __restrict__ out)
{
    const int b    = blockIdx.x;
    const int lane = threadIdx.x;

    float* __restrict__ op = out + (size_t)b * (TT * 65);

    const float Ls = ws[WS_STATS + (size_t)b * NCH + lane];
    const float Le = op[(size_t)(lane * CLEN + CLEN - 1) * 65 + 64];
    const float D  = Le - Ls;

    float O = 0.f;
    #pragma unroll
    for (int j = 0; j < NCH - 1; ++j) {
        const float Dj = __int_as_float(
            __builtin_amdgcn_readlane(__float_as_int(D), j));
        if (lane > j) O += Dj;
    }
    const float offs = O - Ls;

    #pragma unroll
    for (int k = 0; k < 16; ++k) {
        const int row  = k * 64 + lane;
        const int cidx = row >> 4;
        const float offk = __shfl(offs, cidx, 64);
        op[(size_t)row * 65 + 64] += offk;
    }
}

// ---------------------------------------------------------------------------
extern "C" void kernel_launch(void* const* d_in, const int* in_sizes, int n_in,
                              void* d_out, int out_size, void* d_ws, size_t ws_size,
                              hipStream_t stream) {
    const float* inputs = (const float*)d_in[0];  // [512,1024,32]
    const float* em     = (const float*)d_in[1];  // [64,32]
    const float* tr     = (const float*)d_in[2];  // [64,64]
    const float* ini    = (const float*)d_in[3];  // [64]
    float* out = (float*)d_out;                   // [512,1024,65]
    float* ws  = (float*)d_ws;                    // ~42240 floats (~169 KB)

    hmm_prep<<<1, 64, 0, stream>>>(em, tr, ini, ws);
    hmm_scan<<<BATCH * 4, 64, 0, stream>>>(inputs, ws, out);
    hmm_fix<<<BATCH, 64, 0, stream>>>(ws, out);
}

// Round 21
// 64.416 us; speedup vs baseline: 1.0044x; 1.0044x over previous
//
#include <hip/hip_runtime.h>

#define BATCH 512
#define TT    1024
#define NST   64
#define NSYM  32
#define NCH   64      // chunks per chain (4 waves x 16 MFMA columns)
#define CLEN  16      // TT / NCH
#define WARM  6       // warmup steps (mixing 0.16^6 ~ 2e-5; ll err ~2e-3 << 14.5)
#define LN2F  0.69314718055994530942f

#define AP_MV    6400   // dword offset: packed matvec A-frags  [4mt][2kc][64][4]
#define AP_EM    8448   // dword offset: packed emission A-frags [4mt][64][4]
#define WS_STATS 9472   // float offset: per-(chain,chunk) Lstart  [512][64]
#define WS_LEND  42240  // float offset: per-(chain,chunk) Lend    [512][64]

typedef _Float16 f16x8 __attribute__((ext_vector_type(8)));
typedef float    f32x4 __attribute__((ext_vector_type(4)));

#define MFMA_F16(a,b,c) __builtin_amdgcn_mfma_f32_16x16x32_f16(a,b,c,0,0,0)

__device__ __forceinline__ unsigned pkrtz_u(float a, float b) {
    return __builtin_bit_cast(unsigned, __builtin_amdgcn_cvt_pkrtz(a, b));
}

// slot(g, r) -> k within a K=32 chunk (shared by A-pack and B-pack; the k-sum
// is permutation invariant so any true hw map works if both sides agree).
__device__ __forceinline__ int sigma_k(int g, int r) {
    return (r < 4) ? (4 * g + r) : (16 + 4 * g + (r - 4));
}

__device__ __forceinline__ f16x8 pk8(float a0, float a1, float a2, float a3,
                                     float a4, float a5, float a6, float a7) {
    union U { unsigned u[4]; f16x8 v; } u;
    u.u[0] = pkrtz_u(a0, a1);
    u.u[1] = pkrtz_u(a2, a3);
    u.u[2] = pkrtz_u(a4, a5);
    u.u[3] = pkrtz_u(a6, a7);
    return u.v;
}

// xs16 swizzle (u32-index domain): XOR row bits [8:10] into bits [2:4].
// Bijective; preserves bits 0-1 (b64 groups contiguous); spreads the 16
// same-g lanes across 8 bank-classes -> ~2-way conflicts (free, m136).
__device__ __forceinline__ int swz16(int d) { return d ^ (((d >> 8) & 7) << 2); }

// ---------------------------------------------------------------------------
// Prep: softmaxes + MFMA fragment packing (unchanged).
// ---------------------------------------------------------------------------
__global__ __launch_bounds__(64) void hmm_prep(
    const float* __restrict__ em, const float* __restrict__ tr,
    const float* __restrict__ ini, float* __restrict__ ws)
{
    const int n = threadIdx.x;

    {
        float a[64];
        float m = -1e30f;
        #pragma unroll
        for (int j = 0; j < 64; ++j) { a[j] = tr[n * 64 + j]; m = fmaxf(m, a[j]); }
        float s = 0.f;
        #pragma unroll
        for (int j = 0; j < 64; ++j) { a[j] = __expf(a[j] - m); s += a[j]; }
        const float inv = 1.f / s;
        #pragma unroll
        for (int j = 0; j < 64; ++j) ws[n * 64 + j] = a[j] * inv;
    }
    {
        float bv[32];
        float m = -1e30f;
        #pragma unroll
        for (int j = 0; j < 32; ++j) { bv[j] = em[n * 32 + j]; m = fmaxf(m, bv[j]); }
        float s = 0.f;
        #pragma unroll
        for (int j = 0; j < 32; ++j) { bv[j] = __expf(bv[j] - m); s += bv[j]; }
        const float inv = 1.f / s;
        #pragma unroll
        for (int j = 0; j < 32; ++j) ws[4096 + n * 32 + j] = bv[j] * inv;
    }
    {
        float v = ini[n];
        float m = v;
        #pragma unroll
        for (int off = 32; off; off >>= 1) m = fmaxf(m, __shfl_xor(m, off, 64));
        const float e = __expf(v - m);
        float s = e;
        #pragma unroll
        for (int off = 32; off; off >>= 1) s += __shfl_xor(s, off, 64);
        ws[6144 + n] = e / s;
    }

    __syncthreads();

    const int g   = n >> 4;
    const int cl  = n & 15;
    unsigned* wsu = (unsigned*)ws;

    #pragma unroll
    for (int mt = 0; mt < 4; ++mt) {
        #pragma unroll
        for (int kc = 0; kc < 2; ++kc) {
            #pragma unroll
            for (int p = 0; p < 4; ++p) {
                const int k0 = sigma_k(g, 2 * p);
                const int k1 = sigma_k(g, 2 * p + 1);
                const int m  = 16 * mt + cl;
                const float a0 = ws[(32 * kc + k0) * 64 + m];
                const float a1 = ws[(32 * kc + k1) * 64 + m];
                wsu[AP_MV + ((mt * 2 + kc) * 64 + n) * 4 + p] = pkrtz_u(a0, a1);
            }
        }
        #pragma unroll
        for (int p = 0; p < 4; ++p) {
            const int k0 = sigma_k(g, 2 * p);
            const int k1 = sigma_k(g, 2 * p + 1);
            const int st = 16 * mt + cl;
            const float b0 = ws[4096 + st * 32 + k0];
            const float b1 = ws[4096 + st * 32 + k1];
            wsu[AP_EM + (mt * 64 + n) * 4 + p] = pkrtz_u(b0, b1);
        }
    }
}

// ---------------------------------------------------------------------------
// MFMA scan (R19 body): LDS f16-packed x window, chained matvec MFMA,
// uniform per-step power-of-2 rescale, WARM=6.  Epilogue also writes Lend
// to ws so hmm_fix reads stats compactly (no scattered out reads for stats).
// ---------------------------------------------------------------------------
__global__ __launch_bounds__(64, 1) void hmm_scan(
    const float* __restrict__ inputs, float* __restrict__ ws,
    float* __restrict__ out)
{
    const int lane = threadIdx.x;
    const int col  = lane & 15;
    const int g    = lane >> 4;
    const int b    = blockIdx.x >> 2;
    const int w    = blockIdx.x & 3;
    const int c    = 16 * w + col;
    const int t0   = c * CLEN;
    const bool isc0 = (c == 0);

    __shared__ unsigned xs16[272 * 16];   // f16-packed window rows [256w-16, 256w+256)

    f16x8 Amv[4][2], Aem[4];
    {
        const int4* mvp = (const int4*)((const unsigned*)ws + AP_MV);
        const int4* emp = (const int4*)((const unsigned*)ws + AP_EM);
        #pragma unroll
        for (int mt = 0; mt < 4; ++mt) {
            Amv[mt][0] = __builtin_bit_cast(f16x8, mvp[(mt * 2 + 0) * 64 + lane]);
            Amv[mt][1] = __builtin_bit_cast(f16x8, mvp[(mt * 2 + 1) * 64 + lane]);
            Aem[mt]    = __builtin_bit_cast(f16x8, emp[mt * 64 + lane]);
        }
    }

    const float* __restrict__ xp = inputs + (size_t)b * (TT * NSYM);
    float* __restrict__ op       = out    + (size_t)b * (TT * 65);

    // ---- stage + pack x window: 272 rows x 16 u32 ----
    #pragma unroll
    for (int i = 0; i < 17; ++i) {
        const int d   = (i * 64 + lane) * 4;   // u32 index, 4-aligned
        const int row = d >> 4;                // 0..271
        const int sy  = (d & 15) * 2;          // source symbol 0,8,16,24
        int grow = 256 * w - 16 + row;
        grow = grow < 0 ? 0 : grow;
        const float* src = xp + (size_t)grow * 32 + sy;
        const float4 a  = *(const float4*)(src);
        const float4 bq = *(const float4*)(src + 4);
        unsigned* pdst = &xs16[swz16(d)];
        pdst[0] = pkrtz_u(a.x, a.y);
        pdst[1] = pkrtz_u(a.z, a.w);
        pdst[2] = pkrtz_u(bq.x, bq.y);
        pdst[3] = pkrtz_u(bq.z, bq.w);
    }
    __syncthreads();

    // x B-operand for step k: pairs {2g,2g+1, 8+2g,8+2g+1} of window row
    // col*16+k+16 -- matches sigma_k slot layout.
    auto ldx = [&](int k) -> f16x8 {
        const int row = col * 16 + k + 16;
        const int d0  = row * 16 + 2 * g;
        const int d1  = d0 + 8;
        union { unsigned u[4]; f16x8 v; } r;
        const uint2 lo = *(const uint2*)&xs16[swz16(d0)];
        const uint2 hi = *(const uint2*)&xs16[swz16(d1)];
        r.u[0] = lo.x; r.u[1] = lo.y; r.u[2] = hi.x; r.u[3] = hi.y;
        return r.v;
    };

    float hD[4][4];
    #pragma unroll
    for (int mt = 0; mt < 4; ++mt)
        #pragma unroll
        for (int r = 0; r < 4; ++r) hD[mt][r] = 1.0f;
    int Esum = 0;

    const f32x4 z4 = {0.f, 0.f, 0.f, 0.f};

    auto step = [&](int k, bool store_) {
        if (store_) {
            float p = 0.f;
            #pragma unroll
            for (int mt = 0; mt < 4; ++mt)
                #pragma unroll
                for (int r = 0; r < 4; ++r) p += hD[mt][r];
            p += __shfl_xor(p, 16, 64);
            p += __shfl_xor(p, 32, 64);
            const float rS = __builtin_amdgcn_rcpf(p);
            float* rowp = op + (size_t)(t0 + k - 1) * 65;
            #pragma unroll
            for (int mt = 0; mt < 4; ++mt) {
                const float4 v4 = {hD[mt][0] * rS, hD[mt][1] * rS,
                                   hD[mt][2] * rS, hD[mt][3] * rS};
                *(float4*)(rowp + 16 * mt + 4 * g) = v4;
            }
            if (g == 0) rowp[64] = __logf(p) + (float)Esum * LN2F;
        }
        const int pb = __builtin_amdgcn_readlane(__float_as_int(hD[0][0]), 15);
        int ex = (pb >> 23) & 255;
        ex = ex < 1 ? 1 : (ex > 253 ? 253 : ex);
        const float sc = __uint_as_float((unsigned)(254 - ex) << 23);
        Esum += ex - 127;
        const f16x8 bx = ldx(k);
        f32x4 Esc[4];
        #pragma unroll
        for (int mt = 0; mt < 4; ++mt) {
            const f32x4 E = MFMA_F16(Aem[mt], bx, z4);
            Esc[mt][0] = E[0] * sc; Esc[mt][1] = E[1] * sc;
            Esc[mt][2] = E[2] * sc; Esc[mt][3] = E[3] * sc;
        }
        const f16x8 bh0 = pk8(hD[0][0], hD[0][1], hD[0][2], hD[0][3],
                              hD[1][0], hD[1][1], hD[1][2], hD[1][3]);
        const f16x8 bh1 = pk8(hD[2][0], hD[2][1], hD[2][2], hD[2][3],
                              hD[3][0], hD[3][1], hD[3][2], hD[3][3]);
        #pragma unroll
        for (int mt = 0; mt < 4; ++mt) {
            const f32x4 mv = MFMA_F16(Amv[mt][1], bh1,
                              MFMA_F16(Amv[mt][0], bh0, z4));
            hD[mt][0] = Esc[mt][0] * mv[0];
            hD[mt][1] = Esc[mt][1] * mv[1];
            hD[mt][2] = Esc[mt][2] * mv[2];
            hD[mt][3] = Esc[mt][3] * mv[3];
        }
    };

    // warmup k = -6..-1 (no outputs)
    #pragma unroll
    for (int k = -WARM; k < 0; ++k) step(k, false);

    // Lstart (state at t0-1)
    float Lstart;
    {
        float p = 0.f;
        #pragma unroll
        for (int mt = 0; mt < 4; ++mt)
            #pragma unroll
            for (int r = 0; r < 4; ++r) p += hD[mt][r];
        p += __shfl_xor(p, 16, 64);
        p += __shfl_xor(p, 32, 64);
        Lstart = __logf(p) + (float)Esum * LN2F;
    }
    Lstart = isc0 ? 0.f : Lstart;

    // k = 0: silent step (row t0-1 belongs to chunk c-1)
    step(0, false);

    // chunk-0 exact restart: h_0 = E_0 o I   (ldx(0) of col 0 = global row 0)
    {
        const f16x8 bx0 = ldx(0);
        #pragma unroll
        for (int mt = 0; mt < 4; ++mt) {
            const f32x4 E0 = MFMA_F16(Aem[mt], bx0, z4);
            const float4 iv = *(const float4*)(ws + 6144 + 16 * mt + 4 * g);
            const float ivv[4] = {iv.x, iv.y, iv.z, iv.w};
            #pragma unroll
            for (int r = 0; r < 4; ++r)
                if (isc0) hD[mt][r] = E0[r] * ivv[r];
        }
        if (isc0) Esum = 0;
    }

    // main: k = 1..15, outputs for rows t0..t0+14
    #pragma unroll
    for (int k = 1; k <= 15; ++k) step(k, true);

    // epilogue: row t0+15 (local Lend) + stats to ws
    {
        float p = 0.f;
        #pragma unroll
        for (int mt = 0; mt < 4; ++mt)
            #pragma unroll
            for (int r = 0; r < 4; ++r) p += hD[mt][r];
        p += __shfl_xor(p, 16, 64);
        p += __shfl_xor(p, 32, 64);
        const float rS = __builtin_amdgcn_rcpf(p);
        float* rowp = op + (size_t)(t0 + CLEN - 1) * 65;
        #pragma unroll
        for (int mt = 0; mt < 4; ++mt) {
            const float4 v4 = {hD[mt][0] * rS, hD[mt][1] * rS,
                               hD[mt][2] * rS, hD[mt][3] * rS};
            *(float4*)(rowp + 16 * mt + 4 * g) = v4;
        }
        const float Lend = __logf(p) + (float)Esum * LN2F;
        if (g == 0) {
            rowp[64] = Lend;                              // local ll (fix adds offs)
            ws[WS_STATS + (size_t)b * NCH + c] = Lstart;
            ws[WS_LEND  + (size_t)b * NCH + c] = Lend;
        }
    }
}

// ---------------------------------------------------------------------------
// Fixup v2: 4 blocks per chain (grid 2048 = 8 waves/CU).  Each block reads
// the chain's compact {Lstart, Lend} from ws (coalesced), redundantly
// computes the exclusive prefix O_c (63 readlane-adds), then RMWs its
// 256-row quarter: ll[t] += O_{t/16} - Lstart_{t/16}.
// ---------------------------------------------------------------------------
__global__ __launch_bounds__(64) void hmm_fix(
    const float* __restrict__ ws, float* __restrict__ out)
{
    const int b    = blockIdx.x >> 2;
    const int q    = blockIdx.x & 3;    // row quarter
    const int lane = threadIdx.x;       // = chunk index c

    float* __restrict__ op = out + (size_t)b * (TT * 65);

    const float Ls = ws[WS_STATS + (size_t)b * NCH + lane];
    const float Le = ws[WS_LEND  + (size_t)b * NCH + lane];
    const float D  = Le - Ls;

    float O = 0.f;
    #pragma unroll
    for (int j = 0; j < NCH - 1; ++j) {
        const float Dj = __int_as_float(
            __builtin_amdgcn_readlane(__float_as_int(D), j));
        if (lane > j) O += Dj;
    }
    const float offs = O - Ls;

    #pragma unroll
    for (int r = 0; r < 4; ++r) {
        const int row  = q * 256 + r * 64 + lane;
        const int cidx = row >> 4;                     // row / CLEN
        const float offk = __shfl(offs, cidx, 64);
        op[(size_t)row * 65 + 64] += offk;
    }
}

// ---------------------------------------------------------------------------
extern "C" void kernel_launch(void* const* d_in, const int* in_sizes, int n_in,
                              void* d_out, int out_size, void* d_ws, size_t ws_size,
                              hipStream_t stream) {
    const float* inputs = (const float*)d_in[0];  // [512,1024,32]
    const float* em     = (const float*)d_in[1];  // [64,32]
    const float* tr     = (const float*)d_in[2];  // [64,64]
    const float* ini    = (const float*)d_in[3];  // [64]
    float* out = (float*)d_out;                   // [512,1024,65]
    float* ws  = (float*)d_ws;                    // ~75008 floats (~300 KB)

    hmm_prep<<<1, 64, 0, stream>>>(em, tr, ini, ws);
    hmm_scan<<<BATCH * 4, 64, 0, stream>>>(inputs, ws, out);
    hmm_fix<<<BATCH * 4, 64, 0, stream>>>(ws, out);
}

// Round 22
// 61.492 us; speedup vs baseline: 1.0522x; 1.0475x over previous
//
#include <hip/hip_runtime.h>

#define BATCH 512
#define TT    1024
#define NST   64
#define NSYM  32
#define NCH   64      // chunks per chain (4 waves x 16 MFMA columns)
#define CLEN  16      // TT / NCH
#define WARM  8       // warmup steps (mixing 0.16^8 ~ 4e-7, << f16 noise)
#define LN2F  0.69314718055994530942f

#define AP_MV    6400   // dword offset: packed matvec A-frags  [4mt][2kc][64][4]
#define AP_EM    8448   // dword offset: packed emission A-frags [4mt][64][4]
#define WS_STATS 9472   // float offset: per-(chain,chunk) Lstart  [512][64]

typedef _Float16 f16x8 __attribute__((ext_vector_type(8)));
typedef float    f32x4 __attribute__((ext_vector_type(4)));

#define MFMA_F16(a,b,c) __builtin_amdgcn_mfma_f32_16x16x32_f16(a,b,c,0,0,0)

__device__ __forceinline__ unsigned pkrtz_u(float a, float b) {
    return __builtin_bit_cast(unsigned, __builtin_amdgcn_cvt_pkrtz(a, b));
}

// slot(g, r) -> k within a K=32 chunk (shared by A-pack and B-pack; the k-sum
// is permutation invariant so any true hw map works if both sides agree).
__device__ __forceinline__ int sigma_k(int g, int r) {
    return (r < 4) ? (4 * g + r) : (16 + 4 * g + (r - 4));
}

__device__ __forceinline__ f16x8 pk8(float a0, float a1, float a2, float a3,
                                     float a4, float a5, float a6, float a7) {
    union U { unsigned u[4]; f16x8 v; } u;
    u.u[0] = pkrtz_u(a0, a1);
    u.u[1] = pkrtz_u(a2, a3);
    u.u[2] = pkrtz_u(a4, a5);
    u.u[3] = pkrtz_u(a6, a7);
    return u.v;
}

// xs16 swizzle (u32-index domain): XOR row bits [8:10] into bits [2:4].
// Bijective; preserves bits 0-1 (b64 groups contiguous); spreads the 16
// same-g lanes across 8 bank-classes -> ~2-way conflicts (free, m136).
__device__ __forceinline__ int swz16(int d) { return d ^ (((d >> 8) & 7) << 2); }

// ---------------------------------------------------------------------------
// Prep: softmaxes + MFMA fragment packing.
// ---------------------------------------------------------------------------
__global__ __launch_bounds__(64) void hmm_prep(
    const float* __restrict__ em, const float* __restrict__ tr,
    const float* __restrict__ ini, float* __restrict__ ws)
{
    const int n = threadIdx.x;

    {
        float a[64];
        float m = -1e30f;
        #pragma unroll
        for (int j = 0; j < 64; ++j) { a[j] = tr[n * 64 + j]; m = fmaxf(m, a[j]); }
        float s = 0.f;
        #pragma unroll
        for (int j = 0; j < 64; ++j) { a[j] = __expf(a[j] - m); s += a[j]; }
        const float inv = 1.f / s;
        #pragma unroll
        for (int j = 0; j < 64; ++j) ws[n * 64 + j] = a[j] * inv;
    }
    {
        float bv[32];
        float m = -1e30f;
        #pragma unroll
        for (int j = 0; j < 32; ++j) { bv[j] = em[n * 32 + j]; m = fmaxf(m, bv[j]); }
        float s = 0.f;
        #pragma unroll
        for (int j = 0; j < 32; ++j) { bv[j] = __expf(bv[j] - m); s += bv[j]; }
        const float inv = 1.f / s;
        #pragma unroll
        for (int j = 0; j < 32; ++j) ws[4096 + n * 32 + j] = bv[j] * inv;
    }
    {
        float v = ini[n];
        float m = v;
        #pragma unroll
        for (int off = 32; off; off >>= 1) m = fmaxf(m, __shfl_xor(m, off, 64));
        const float e = __expf(v - m);
        float s = e;
        #pragma unroll
        for (int off = 32; off; off >>= 1) s += __shfl_xor(s, off, 64);
        ws[6144 + n] = e / s;
    }

    __syncthreads();

    const int g   = n >> 4;
    const int cl  = n & 15;
    unsigned* wsu = (unsigned*)ws;

    #pragma unroll
    for (int mt = 0; mt < 4; ++mt) {
        #pragma unroll
        for (int kc = 0; kc < 2; ++kc) {
            #pragma unroll
            for (int p = 0; p < 4; ++p) {
                const int k0 = sigma_k(g, 2 * p);
                const int k1 = sigma_k(g, 2 * p + 1);
                const int m  = 16 * mt + cl;
                const float a0 = ws[(32 * kc + k0) * 64 + m];
                const float a1 = ws[(32 * kc + k1) * 64 + m];
                wsu[AP_MV + ((mt * 2 + kc) * 64 + n) * 4 + p] = pkrtz_u(a0, a1);
            }
        }
        #pragma unroll
        for (int p = 0; p < 4; ++p) {
            const int k0 = sigma_k(g, 2 * p);
            const int k1 = sigma_k(g, 2 * p + 1);
            const int st = 16 * mt + cl;
            const float b0 = ws[4096 + st * 32 + k0];
            const float b1 = ws[4096 + st * 32 + k1];
            wsu[AP_EM + (mt * 64 + n) * 4 + p] = pkrtz_u(b0, b1);
        }
    }
}

// ---------------------------------------------------------------------------
// MFMA scan (R19-best): x window staged ONCE into LDS as PACKED f16 (17.4 KB).
// Per step the B-operand for the emission MFMA is two swizzled ds_read_b64;
// matvec uses chained MFMA (C-accumulate); uniform per-step power-of-2
// rescale; WARM=8; delayed outputs; Lstart/Lend telescoping via hmm_fix.
// ---------------------------------------------------------------------------
__global__ __launch_bounds__(64, 1) void hmm_scan(
    const float* __restrict__ inputs, float* __restrict__ ws,
    float* __restrict__ out)
{
    const int lane = threadIdx.x;
    const int col  = lane & 15;
    const int g    = lane >> 4;
    const int b    = blockIdx.x >> 2;
    const int w    = blockIdx.x & 3;
    const int c    = 16 * w + col;
    const int t0   = c * CLEN;
    const bool isc0 = (c == 0);

    __shared__ unsigned xs16[272 * 16];   // f16-packed window rows [256w-16, 256w+256)

    f16x8 Amv[4][2], Aem[4];
    {
        const int4* mvp = (const int4*)((const unsigned*)ws + AP_MV);
        const int4* emp = (const int4*)((const unsigned*)ws + AP_EM);
        #pragma unroll
        for (int mt = 0; mt < 4; ++mt) {
            Amv[mt][0] = __builtin_bit_cast(f16x8, mvp[(mt * 2 + 0) * 64 + lane]);
            Amv[mt][1] = __builtin_bit_cast(f16x8, mvp[(mt * 2 + 1) * 64 + lane]);
            Aem[mt]    = __builtin_bit_cast(f16x8, emp[mt * 64 + lane]);
        }
    }

    const float* __restrict__ xp = inputs + (size_t)b * (TT * NSYM);
    float* __restrict__ op       = out    + (size_t)b * (TT * 65);

    // ---- stage + pack x window: 272 rows x 16 u32 (68 u32/lane) ----
    #pragma unroll
    for (int i = 0; i < 17; ++i) {
        const int d   = (i * 64 + lane) * 4;   // u32 index, 4-aligned
        const int row = d >> 4;                // 0..271
        const int sy  = (d & 15) * 2;          // source symbol 0,8,16,24
        int grow = 256 * w - 16 + row;
        grow = grow < 0 ? 0 : grow;
        const float* src = xp + (size_t)grow * 32 + sy;
        const float4 a  = *(const float4*)(src);
        const float4 bq = *(const float4*)(src + 4);
        unsigned* pdst = &xs16[swz16(d)];
        pdst[0] = pkrtz_u(a.x, a.y);
        pdst[1] = pkrtz_u(a.z, a.w);
        pdst[2] = pkrtz_u(bq.x, bq.y);
        pdst[3] = pkrtz_u(bq.z, bq.w);
    }
    __syncthreads();

    // x B-operand for step k: pairs {2g,2g+1, 8+2g,8+2g+1} of window row
    // col*16+k+16 -- matches sigma_k slot layout.
    auto ldx = [&](int k) -> f16x8 {
        const int row = col * 16 + k + 16;
        const int d0  = row * 16 + 2 * g;
        const int d1  = d0 + 8;
        union { unsigned u[4]; f16x8 v; } r;
        const uint2 lo = *(const uint2*)&xs16[swz16(d0)];
        const uint2 hi = *(const uint2*)&xs16[swz16(d1)];
        r.u[0] = lo.x; r.u[1] = lo.y; r.u[2] = hi.x; r.u[3] = hi.y;
        return r.v;
    };

    float hD[4][4];
    #pragma unroll
    for (int mt = 0; mt < 4; ++mt)
        #pragma unroll
        for (int r = 0; r < 4; ++r) hD[mt][r] = 1.0f;
    int Esum = 0;

    const f32x4 z4 = {0.f, 0.f, 0.f, 0.f};

    auto step = [&](int k, bool store_) {
        if (store_) {
            float p = 0.f;
            #pragma unroll
            for (int mt = 0; mt < 4; ++mt)
                #pragma unroll
                for (int r = 0; r < 4; ++r) p += hD[mt][r];
            p += __shfl_xor(p, 16, 64);
            p += __shfl_xor(p, 32, 64);
            const float rS = __builtin_amdgcn_rcpf(p);
            float* rowp = op + (size_t)(t0 + k - 1) * 65;
            #pragma unroll
            for (int mt = 0; mt < 4; ++mt) {
                const float4 v4 = {hD[mt][0] * rS, hD[mt][1] * rS,
                                   hD[mt][2] * rS, hD[mt][3] * rS};
                *(float4*)(rowp + 16 * mt + 4 * g) = v4;
            }
            if (g == 0) rowp[64] = __logf(p) + (float)Esum * LN2F;
        }
        const int pb = __builtin_amdgcn_readlane(__float_as_int(hD[0][0]), 15);
        int ex = (pb >> 23) & 255;
        ex = ex < 1 ? 1 : (ex > 253 ? 253 : ex);
        const float sc = __uint_as_float((unsigned)(254 - ex) << 23);
        Esum += ex - 127;
        const f16x8 bx = ldx(k);
        f32x4 Esc[4];
        #pragma unroll
        for (int mt = 0; mt < 4; ++mt) {
            const f32x4 E = MFMA_F16(Aem[mt], bx, z4);
            Esc[mt][0] = E[0] * sc; Esc[mt][1] = E[1] * sc;
            Esc[mt][2] = E[2] * sc; Esc[mt][3] = E[3] * sc;
        }
        const f16x8 bh0 = pk8(hD[0][0], hD[0][1], hD[0][2], hD[0][3],
                              hD[1][0], hD[1][1], hD[1][2], hD[1][3]);
        const f16x8 bh1 = pk8(hD[2][0], hD[2][1], hD[2][2], hD[2][3],
                              hD[3][0], hD[3][1], hD[3][2], hD[3][3]);
        #pragma unroll
        for (int mt = 0; mt < 4; ++mt) {
            const f32x4 mv = MFMA_F16(Amv[mt][1], bh1,
                              MFMA_F16(Amv[mt][0], bh0, z4));
            hD[mt][0] = Esc[mt][0] * mv[0];
            hD[mt][1] = Esc[mt][1] * mv[1];
            hD[mt][2] = Esc[mt][2] * mv[2];
            hD[mt][3] = Esc[mt][3] * mv[3];
        }
    };

    // warmup k = -8..-1 (no outputs)
    #pragma unroll 4
    for (int k = -WARM; k < 0; ++k) step(k, false);

    // Lstart (state at t0-1)
    float Lstart;
    {
        float p = 0.f;
        #pragma unroll
        for (int mt = 0; mt < 4; ++mt)
            #pragma unroll
            for (int r = 0; r < 4; ++r) p += hD[mt][r];
        p += __shfl_xor(p, 16, 64);
        p += __shfl_xor(p, 32, 64);
        Lstart = __logf(p) + (float)Esum * LN2F;
    }
    Lstart = isc0 ? 0.f : Lstart;

    // k = 0: silent step (row t0-1 belongs to chunk c-1)
    step(0, false);

    // chunk-0 exact restart: h_0 = E_0 o I   (ldx(0) of col 0 = global row 0)
    {
        const f16x8 bx0 = ldx(0);
        #pragma unroll
        for (int mt = 0; mt < 4; ++mt) {
            const f32x4 E0 = MFMA_F16(Aem[mt], bx0, z4);
            const float4 iv = *(const float4*)(ws + 6144 + 16 * mt + 4 * g);
            const float ivv[4] = {iv.x, iv.y, iv.z, iv.w};
            #pragma unroll
            for (int r = 0; r < 4; ++r)
                if (isc0) hD[mt][r] = E0[r] * ivv[r];
        }
        if (isc0) Esum = 0;
    }

    // main: k = 1..15, outputs for rows t0..t0+14
    #pragma unroll
    for (int k = 1; k <= 15; ++k) step(k, true);

    // epilogue: row t0+15 (local Lend) + Lstart stat
    {
        float p = 0.f;
        #pragma unroll
        for (int mt = 0; mt < 4; ++mt)
            #pragma unroll
            for (int r = 0; r < 4; ++r) p += hD[mt][r];
        p += __shfl_xor(p, 16, 64);
        p += __shfl_xor(p, 32, 64);
        const float rS = __builtin_amdgcn_rcpf(p);
        float* rowp = op + (size_t)(t0 + CLEN - 1) * 65;
        #pragma unroll
        for (int mt = 0; mt < 4; ++mt) {
            const float4 v4 = {hD[mt][0] * rS, hD[mt][1] * rS,
                               hD[mt][2] * rS, hD[mt][3] * rS};
            *(float4*)(rowp + 16 * mt + 4 * g) = v4;
        }
        if (g == 0) {
            rowp[64] = __logf(p) + (float)Esum * LN2F;   // local Lend
            ws[WS_STATS + (size_t)b * NCH + c] = Lstart;
        }
    }
}

// ---------------------------------------------------------------------------
// Fixup: per chain, D_c = Lend_c(local, from out) - Lstart_c; exclusive prefix
// O_c; ll[t] += O_{t/16} - Lstart_{t/16}.  Chunk 0: O=0, Ls=0.
// ---------------------------------------------------------------------------
__global__ __launch_bounds__(64) void hmm_fix(
    const float* __restrict__ ws, float* __restrict__ out)
{
    const int b    = blockIdx.x;
    const int lane = threadIdx.x;

    float* __restrict__ op = out + (size_t)b * (TT * 65);

    const float Ls = ws[WS_STATS + (size_t)b * NCH + lane];
    const float Le = op[(size_t)(lane * CLEN + CLEN - 1) * 65 + 64];
    const float D  = Le - Ls;

    float O = 0.f;
    #pragma unroll
    for (int j = 0; j < NCH - 1; ++j) {
        const float Dj = __int_as_float(
            __builtin_amdgcn_readlane(__float_as_int(D), j));
        if (lane > j) O += Dj;
    }
    const float offs = O - Ls;

    #pragma unroll
    for (int k = 0; k < 16; ++k) {
        const int row  = k * 64 + lane;
        const int cidx = row >> 4;
        const float offk = __shfl(offs, cidx, 64);
        op[(size_t)row * 65 + 64] += offk;
    }
}

// ---------------------------------------------------------------------------
extern "C" void kernel_launch(void* const* d_in, const int* in_sizes, int n_in,
                              void* d_out, int out_size, void* d_ws, size_t ws_size,
                              hipStream_t stream) {
    const float* inputs = (const float*)d_in[0];  // [512,1024,32]
    const float* em     = (const float*)d_in[1];  // [64,32]
    const float* tr     = (const float*)d_in[2];  // [64,64]
    const float* ini    = (const float*)d_in[3];  // [64]
    float* out = (float*)d_out;                   // [512,1024,65]
    float* ws  = (float*)d_ws;                    // ~42240 floats (~169 KB)

    hmm_prep<<<1, 64, 0, stream>>>(em, tr, ini, ws);
    hmm_scan<<<BATCH * 4, 64, 0, stream>>>(inputs, ws, out);
    hmm_fix<<<BATCH, 64, 0, stream>>>(ws, out);
}